// Round 10
// baseline (718.658 us; speedup 1.0000x reference)
//
#include <hip/hip_runtime.h>

// ---------------------------------------------------------------- types/helpers
using frag_ab = __attribute__((ext_vector_type(8))) short;   // bf16x8 MFMA operand
using f4v     = __attribute__((ext_vector_type(4))) float;   // MFMA accumulator
using u8v     = __attribute__((ext_vector_type(8))) unsigned short;
using u4v     = __attribute__((ext_vector_type(4))) unsigned short;

__device__ __forceinline__ float b2f(unsigned short u){
  return __uint_as_float(((unsigned int)u) << 16);
}
__device__ __forceinline__ unsigned short f2b(float f){
  unsigned int x = __float_as_uint(f);
  unsigned int r = x + 0x7fffu + ((x >> 16) & 1u);
  return (unsigned short)(r >> 16);
}
__device__ __forceinline__ float h2f(unsigned short u){
  _Float16 h; __builtin_memcpy(&h, &u, 2); return (float)h;
}
__device__ __forceinline__ unsigned short f2h(float f){
  _Float16 h = (_Float16)f; unsigned short u; __builtin_memcpy(&u, &h, 2); return u;
}
__device__ __forceinline__ float hexp2(float x){
#if __has_builtin(__builtin_amdgcn_exp2f)
  return __builtin_amdgcn_exp2f(x);
#else
  return exp2f(x);
#endif
}
__device__ __forceinline__ float hrcp(float x){
#if __has_builtin(__builtin_amdgcn_rcpf)
  return __builtin_amdgcn_rcpf(x);
#else
  return 1.0f / x;
#endif
}
__device__ __forceinline__ unsigned int cvtpk(float lo, float hi){
  unsigned int r;
  asm("v_cvt_pk_bf16_f32 %0, %1, %2" : "=v"(r) : "v"(lo), "v"(hi));
  return r;
}
// async global->LDS, 16B per lane; dest must be linear (wave base + lane*16)
__device__ __forceinline__ void gl16(const void* g, void* l){
  __builtin_amdgcn_global_load_lds(
      (const __attribute__((address_space(1))) unsigned int*)g,
      (__attribute__((address_space(3))) unsigned int*)l, 16, 0, 0);
}

#define MFMA_BF16 __builtin_amdgcn_mfma_f32_16x16x32_bf16

// ---------------------------------------------------------------- ws layout (bytes)
static constexpr size_t OFF_T   = 0;                       // t f16 [32768][256]
static constexpr size_t OFF_R1  = 33554432ull;             // Xp | q+k | g (mlp hidden)
static constexpr size_t OFF_V   = OFF_R1 + 37748736ull;    // (free)
static constexpr size_t OFF_VT  = OFF_V + 16777216ull;     // vT (permuted)
static constexpr size_t OFF_ZH  = OFF_VT + 16777216ull;    // z | o | znext
static constexpr size_t OFF_A   = OFF_ZH + 16777216ull;    // a bf16 [32768][128]
static constexpr size_t OFF_WB  = OFF_A + 8388608ull;      // converted weights
static constexpr size_t WB_CONVW = 0;          // 256*576*2
static constexpr size_t WB_QKVW  = 294912;     // 4*768*256*2
static constexpr size_t WB_PROJW = 1867776;    // (kept for prep_k layout)
static constexpr size_t WB_MLP1W = 2392064;    // 4*512*256*2
static constexpr size_t WB_MLP2W = 3440640;    // 4*256*512*2
static constexpr size_t WB_W1    = 4489216;    // 4*128*256*2 (pre-scaled by log2e)
static constexpr size_t WB_W2T   = 4751360;    // 4*256*128*2
static constexpr size_t WB_BLOG  = 5013504;    // 4*128 f32 (pre-scaled by log2e)
static constexpr size_t WB_CS    = 5015552;    // 256 f32
static constexpr size_t WB_CSH   = 5016576;    // 256 f32
static constexpr size_t WB_BIASP = 5017600;    // 10*4*65536*2 premasked,*log2e
static constexpr size_t WB_PW2   = WB_BIASP + 5242880;  // projW2 combined [4][256][384]*2
static constexpr size_t WB_PB2   = WB_PW2 + 786432;     // pb2 [4][256] f32

// ---------------------------------------------------------------- prep
__global__ __launch_bounds__(256) void prep_k(
    const float* __restrict__ conv_w, const float* __restrict__ bn_g, const float* __restrict__ bn_b,
    const float* __restrict__ bn_m, const float* __restrict__ bn_v,
    const float* __restrict__ qkv_w, const float* __restrict__ proj_w,
    const float* __restrict__ mlp_w1, const float* __restrict__ mlp_w2,
    const float* __restrict__ mem_b, const float* __restrict__ down_w, const float* __restrict__ down_b,
    const float* __restrict__ up_w, const float* __restrict__ rpb,
    unsigned short* convwb, unsigned short* qkvwb, unsigned short* projwb,
    unsigned short* mlp1wb, unsigned short* mlp2wb, unsigned short* W1b, unsigned short* W2Tb,
    unsigned short* biasPb, float* blogf, float* convS, float* convSh)
{
  int idx = blockIdx.x * 256 + threadIdx.x;
  if (idx < 256){
    float s = bn_g[idx] * rsqrtf(bn_v[idx] + 1e-5f);
    convS[idx] = s; convSh[idx] = bn_b[idx] - bn_m[idx] * s; return;
  }
  idx -= 256;
  if (idx < 147456){  // conv weight reorder: [co][t9*64+ci]
    int co = idx / 576, kk = idx % 576;
    int t9 = kk >> 6, ci = kk & 63, ky = t9 / 3, kx = t9 % 3;
    convwb[idx] = f2b(conv_w[((co*64 + ci)*3 + ky)*3 + kx]); return;
  }
  idx -= 147456;
  if (idx < 786432){ qkvwb[idx] = f2b(qkv_w[idx]); return; }
  idx -= 786432;
  if (idx < 262144){ projwb[idx] = f2b(proj_w[idx]); return; }
  idx -= 262144;
  if (idx < 524288){ mlp1wb[idx] = f2b(mlp_w1[idx]); return; }
  idx -= 524288;
  if (idx < 524288){ mlp2wb[idx] = f2b(mlp_w2[idx]); return; }
  idx -= 524288;
  if (idx < 131072){  // W1[i][s][c] = log2e * sum_j mem[i][s][j]*down[i][j][c]
    int i = idx >> 15, rem = idx & 32767, s = rem >> 8, c = rem & 255;
    float acc = 0.f;
    for (int j = 0; j < 32; ++j) acc += mem_b[(i*128 + s)*32 + j] * down_w[(i*32 + j)*256 + c];
    W1b[idx] = f2b(acc * 1.44269504f); return;
  }
  idx -= 131072;
  if (idx < 131072){  // W2T[i][c][s] = sum_j mem[i][s][j]*up[i][c][j]
    int i = idx >> 15, rem = idx & 32767, c = rem >> 7, s = rem & 127;
    float acc = 0.f;
    for (int j = 0; j < 32; ++j) acc += mem_b[(i*128 + s)*32 + j] * up_w[(i*256 + c)*32 + j];
    W2Tb[idx] = f2b(acc); return;
  }
  idx -= 131072;
  if (idx < 512){  // blog[i][s] = log2e * mem[i][s]·down_b[i]
    int i = idx >> 7, s = idx & 127;
    float acc = 0.f;
    for (int j = 0; j < 32; ++j) acc += mem_b[(i*128 + s)*32 + j] * down_b[i*32 + j];
    blogf[idx] = acc * 1.44269504f; return;
  }
  idx -= 512;
  if (idx < 2621440){  // premasked bias tables [t][h][qb][kb][q15][cm], * log2(e)
    int t = idx >> 18, h = (idx >> 16) & 3, rest = idx & 65535;
    int qb = rest >> 12, kb = (rest >> 8) & 15, q15 = (rest >> 4) & 15, cm = rest & 15;
    int layer, var;
    if (t == 0){ layer = 0; var = 0; }
    else if (t <= 4){ layer = 1; var = t - 1; }
    else if (t == 5){ layer = 2; var = 0; }
    else { layer = 3; var = t - 6; }
    int ri = (qb - kb + 15)*31 + (q15 - cm + 15);
    float b = rpb[((size_t)layer*961 + ri)*4 + h];
    bool mk = ((var & 2) && ((qb < 8) != (kb < 8))) || ((var & 1) && ((q15 < 8) != (cm < 8)));
    if (mk) b -= 100.0f;
    biasPb[idx] = f2b(b * 1.44269504f);
  }
}

// prep2: combined proj|mem-recon weight  W'[i][o][0:256]=proj_w, [256:384]=0.1*(proj_w@W2T)
__global__ __launch_bounds__(256) void prep2_k(const float* __restrict__ proj_w,
    const float* __restrict__ up_b, const float* __restrict__ proj_b,
    const unsigned short* __restrict__ W2Tb, unsigned short* __restrict__ pw2, float* __restrict__ pb2)
{
  int idx = blockIdx.x * 256 + threadIdx.x;
  if (idx < 1024){  // pb2[i][o] = proj_b + 0.1 * up_b @ proj_w^T
    int i = idx >> 8, o = idx & 255;
    float acc = proj_b[i*256 + o];
    for (int c = 0; c < 256; ++c) acc += 0.1f * up_b[i*256 + c] * proj_w[((size_t)(i*256 + o))*256 + c];
    pb2[idx] = acc; return;
  }
  idx -= 1024;
  if (idx < 262144){  // proj part
    int i = idx >> 16, rem = idx & 65535, o = rem >> 8, c = rem & 255;
    pw2[((size_t)(i*256 + o))*384 + c] = f2b(proj_w[((size_t)(i*256 + o))*256 + c]); return;
  }
  idx -= 262144;
  if (idx < 131072){  // Wc part
    int i = idx >> 15, rem = idx & 32767, o = rem >> 7, s = rem & 127;
    float acc = 0.f;
    for (int c = 0; c < 256; ++c)
      acc += proj_w[((size_t)(i*256 + o))*256 + c] * b2f(W2Tb[(i*256 + c)*128 + s]);
    pw2[((size_t)(i*256 + o))*384 + 256 + s] = f2b(0.1f * acc);
  }
}

// ---------------------------------------------------------------- pad: NCHW f32 -> padded NHWC bf16 [8][66][66][64]
__global__ __launch_bounds__(256) void pad_k(const float* __restrict__ x, unsigned short* __restrict__ xp)
{
  const int bid = blockIdx.x;           // 8*66
  const int b = bid / 66, hp = bid % 66;
  const int tid = threadIdx.x;
  unsigned short* orow = xp + ((size_t)(b*66 + hp))*66*64;
  const u8v Z8 = {0,0,0,0,0,0,0,0};
  if (hp == 0 || hp == 65){
    for (int s = tid; s < 528; s += 256) *(u8v*)&orow[s*8] = Z8;
    return;
  }
  __shared__ float ls[64][65];
  const int h = hp - 1;
  {
    int cc = tid >> 2, w4 = (tid & 3)*16;
    const float* src = &x[((size_t)(b*64 + cc)*64 + h)*64 + w4];
    #pragma unroll
    for (int j = 0; j < 4; ++j){
      float4 v = *(const float4*)&src[j*4];
      ls[w4 + j*4 + 0][cc] = v.x; ls[w4 + j*4 + 1][cc] = v.y;
      ls[w4 + j*4 + 2][cc] = v.z; ls[w4 + j*4 + 3][cc] = v.w;
    }
  }
  __syncthreads();
  if (tid < 16){
    int wp = (tid >> 3) * 65;
    *(u8v*)&orow[(size_t)wp*64 + (tid & 7)*8] = Z8;
  }
  int w = tid >> 2, c0 = (tid & 3)*16;
  u8v o0, o1;
  #pragma unroll
  for (int e = 0; e < 8; ++e){ o0[e] = f2b(ls[w][c0+e]); o1[e] = f2b(ls[w][c0+8+e]); }
  *(u8v*)&orow[(size_t)(w+1)*64 + c0] = o0;
  *(u8v*)&orow[(size_t)(w+1)*64 + c0 + 8] = o1;
}

// ---------------------------------------------------------------- unified GEMM, fused epilogues
// trunk t is f16 (unsigned short storage)
struct Ep {
  const float* c0; const float* c1;
  const float* lg; const float* lb;
  unsigned short* t; float* outp;
  unsigned short* o0; unsigned short* o2;
  unsigned short* q; unsigned short* k; unsigned short* v;
  const unsigned short* in0;
  int shift;
};
enum { M_CONV=0, M_QKV=1, M_MEM1S=2, M_MLP2LN=5, M_MLP2OUT=6 };

template<int MODE, int TM, int TN, int KC, int NT, int GX>
__global__ __launch_bounds__(NT) void g512_k(const unsigned short* __restrict__ X,
                                             const unsigned short* __restrict__ W, Ep ep)
{
  __shared__ __align__(16) unsigned short Als[2][TM*32];
  __shared__ __align__(16) unsigned short Bls[2][TN*32];
  const int tid = threadIdx.x, wid = tid >> 6, lane = tid & 63, g = lane >> 4, l15 = lane & 15;
  constexpr int NW = TN/64;
  const int wr = wid / NW, wc = wid % NW;
  const int row0 = (GX ? blockIdx.y : blockIdx.x) * TM;
  const int col0 = (GX ? blockIdx.x : blockIdx.y) * TN;
  constexpr int KT = KC >> 5;
  constexpr int NA = (TM*4)/NT, NB = (TN*4)/NT;

  const unsigned short* gA[NA]; int rbA[NA];
  #pragma unroll
  for (int i = 0; i < NA; ++i){
    int s = tid + NT*i, r = s >> 2, p = s & 3, lb = p ^ ((r >> 1) & 3);
    if constexpr (MODE == M_CONV){
      int ar = row0 + r, bi = ar >> 12, h = (ar >> 6) & 63, w = ar & 63;
      rbA[i] = ((bi*66 + h + 1)*66 + (w + 1))*64 + lb*8; gA[i] = nullptr;
    } else {
      gA[i] = &X[(size_t)(row0 + r)*KC + lb*8]; rbA[i] = 0;
    }
  }
  const unsigned short* gB[NB];
  #pragma unroll
  for (int i = 0; i < NB; ++i){
    int s = tid + NT*i, r = s >> 2, p = s & 3, lb = p ^ ((r >> 1) & 3);
    gB[i] = &W[(size_t)(col0 + r)*KC + lb*8];
  }

  f4v acc[4][4] = {};

  auto stage = [&](int kt, int buf){
    #pragma unroll
    for (int i = 0; i < NA; ++i){
      if constexpr (MODE == M_CONV){
        int t9 = kt >> 1, ky = t9 / 3, kx = t9 - ky*3;
        int koff = ((ky - 1)*66 + (kx - 1))*64 + (kt & 1)*32;
        gl16(X + rbA[i] + koff, &Als[buf][(tid + NT*i)*8]);
      } else {
        gl16(gA[i] + kt*32, &Als[buf][(tid + NT*i)*8]);
      }
    }
    #pragma unroll
    for (int i = 0; i < NB; ++i) gl16(gB[i] + kt*32, &Bls[buf][(tid + NT*i)*8]);
  };
  auto compute = [&](const unsigned short* A, const unsigned short* B){
    frag_ab af[4], bv[4];
    #pragma unroll
    for (int a = 0; a < 4; ++a){ int r = wr*64 + a*16 + l15; int pb = g ^ ((r >> 1) & 3);
      af[a] = *(const frag_ab*)&A[r*32 + pb*8]; }
    #pragma unroll
    for (int b = 0; b < 4; ++b){ int r = wc*64 + b*16 + l15; int pb = g ^ ((r >> 1) & 3);
      bv[b] = *(const frag_ab*)&B[r*32 + pb*8]; }
    #pragma unroll
    for (int a = 0; a < 4; ++a)
      #pragma unroll
      for (int b = 0; b < 4; ++b)
        acc[a][b] = MFMA_BF16(af[a], bv[b], acc[a][b], 0, 0, 0);
  };

  stage(0, 0);
  __syncthreads();
  for (int kt = 0; kt < KT; kt += 2){
    stage(kt + 1, 1);
    compute(Als[0], Bls[0]);
    __syncthreads();
    if (kt + 2 < KT) stage(kt + 2, 0);
    compute(Als[1], Bls[1]);
    __syncthreads();
  }

  float* red = (float*)&Als[0][0];

  if constexpr (MODE == M_QKV){
    const int which = col0 >> 8;          // 0=Q 1=K 2=V
    #pragma unroll
    for (int a = 0; a < 4; ++a){
      #pragma unroll
      for (int b = 0; b < 4; ++b){
        const int grow0 = row0 + wr*64 + a*16 + g*4;
        const int hd = b*16 + l15;
        const float bv = ep.c0[col0 + wc*64 + hd];
        if (which == 2){
          int tok0 = grow0 & 255;
          int pos = (tok0 & ~31) | ((tok0 & 12) << 1) | ((tok0 & 16) >> 2);
          u4v o;
          #pragma unroll
          for (int r = 0; r < 4; ++r) o[r] = f2b(acc[a][b][r] + bv);
          *(u4v*)&ep.v[(((size_t)((grow0 >> 8)*4 + wc)*64 + hd)*256) + pos] = o;
        } else {
          unsigned short* dst = (which == 0) ? ep.q : ep.k;
          float sc = (which == 0) ? 0.18033688f : 1.0f;   // 0.125 * log2(e) folded into Q
          #pragma unroll
          for (int r = 0; r < 4; ++r){
            int grow = grow0 + r;
            dst[(((size_t)(grow >> 8)*4 + wc)*256 + (grow & 255))*64 + hd] = f2b((acc[a][b][r] + bv) * sc);
          }
        }
      }
    }
  } else if constexpr (MODE == M_MEM1S){
    #pragma unroll
    for (int a = 0; a < 4; ++a){
      #pragma unroll
      for (int r = 0; r < 4; ++r){
        float s1 = 0.f;
        #pragma unroll
        for (int b = 0; b < 4; ++b){
          int bcol = wc*64 + b*16 + l15;
          float e = hexp2(acc[a][b][r] + ep.c0[bcol]);
          acc[a][b][r] = e; s1 += e;
        }
        s1 += __shfl_xor(s1, 1); s1 += __shfl_xor(s1, 2);
        s1 += __shfl_xor(s1, 4); s1 += __shfl_xor(s1, 8);
        if (l15 == 0){
          int rl = wr*64 + a*16 + g*4 + r;
          red[rl*NW + wc] = s1;
        }
      }
    }
    __syncthreads();
    #pragma unroll
    for (int a = 0; a < 4; ++a){
      #pragma unroll
      for (int r = 0; r < 4; ++r){
        int rl = wr*64 + a*16 + g*4 + r;
        float inv = 1.0f / (red[rl*NW] + red[rl*NW + 1]);
        int grow = row0 + rl;
        #pragma unroll
        for (int b = 0; b < 4; ++b){
          int bcol = wc*64 + b*16 + l15;
          ep.o0[(size_t)grow*128 + bcol] = f2b(acc[a][b][r] * inv);
        }
      }
    }
  } else if constexpr (MODE == M_MLP2OUT){
    // last layer: t_new written straight to NCHW f32 output
    #pragma unroll
    for (int a = 0; a < 4; ++a){
      #pragma unroll
      for (int b = 0; b < 4; ++b){
        const int grow0 = row0 + wr*64 + a*16 + g*4;
        const int bcol = wc*64 + b*16 + l15;
        float4 vv;
        #pragma unroll
        for (int r = 0; r < 4; ++r)
          (&vv.x)[r] = h2f(ep.t[(size_t)(grow0 + r)*256 + bcol]) + acc[a][b][r] + ep.c0[bcol];
        *(float4*)&ep.outp[((size_t)((grow0 >> 12)*256 + bcol))*4096 + (grow0 & 4095)] = vv;
      }
    }
  } else {
    // M_CONV / M_MLP2LN : t_new (f16) + fused LayerNorm -> windowed z
    #pragma unroll
    for (int a = 0; a < 4; ++a){
      #pragma unroll
      for (int r = 0; r < 4; ++r){
        const int grow = row0 + wr*64 + a*16 + g*4 + r;
        float s1 = 0.f, s2 = 0.f;
        #pragma unroll
        for (int b = 0; b < 4; ++b){
          int bcol = wc*64 + b*16 + l15;
          float v = acc[a][b][r];
          if constexpr (MODE == M_CONV) v = fmaxf(v*ep.c0[bcol] + ep.c1[bcol], 0.f);
          else v = h2f(ep.t[(size_t)grow*256 + bcol]) + v + ep.c0[bcol];
          acc[a][b][r] = v;
          ep.t[(size_t)grow*256 + bcol] = f2h(v);
          s1 += v; s2 += v*v;
        }
        s1 += __shfl_xor(s1, 1); s2 += __shfl_xor(s2, 1);
        s1 += __shfl_xor(s1, 2); s2 += __shfl_xor(s2, 2);
        s1 += __shfl_xor(s1, 4); s2 += __shfl_xor(s2, 4);
        s1 += __shfl_xor(s1, 8); s2 += __shfl_xor(s2, 8);
        if (l15 == 0){
          int rl = wr*64 + a*16 + g*4 + r;
          red[rl*8 + wc*2]     = s1;
          red[rl*8 + wc*2 + 1] = s2;
        }
      }
    }
    __syncthreads();
    #pragma unroll
    for (int a = 0; a < 4; ++a){
      #pragma unroll
      for (int r = 0; r < 4; ++r){
        const int grow = row0 + wr*64 + a*16 + g*4 + r;
        int rl = wr*64 + a*16 + g*4 + r;
        float s1 = red[rl*8] + red[rl*8+2] + red[rl*8+4] + red[rl*8+6];
        float s2 = red[rl*8+1] + red[rl*8+3] + red[rl*8+5] + red[rl*8+7];
        float mu = s1 * (1.0f/256.0f);
        float var = s2 * (1.0f/256.0f) - mu*mu;
        float rstd = rsqrtf(var + 1e-5f);
        unsigned short* zo = (MODE == M_MLP2LN) ? ep.o2 : ep.o0;
        int bb2 = grow >> 12, h = (grow >> 6) & 63, w = grow & 63;
        int hs = (h - ep.shift) & 63, ws = (w - ep.shift) & 63;
        int drow = (bb2*16 + (hs >> 4)*4 + (ws >> 4))*256 + (hs & 15)*16 + (ws & 15);
        #pragma unroll
        for (int b = 0; b < 4; ++b){
          int bcol = wc*64 + b*16 + l15;
          float v = acc[a][b][r];
          zo[(size_t)drow*256 + bcol] = f2b((v - mu)*rstd*ep.lg[bcol] + ep.lb[bcol]);
        }
      }
    }
  }
}

// ---------------------------------------------------------------- fused PROJ(+mem)+LN2+MLP1 kernel
// phase 1: t += [o|a] @ pw2^T + pb2  (K=384), LN2 -> h in LDS (staging layout)
// phase 2: g = gelu(h @ mlp_w1^T + mb1), 2 col-blocks of 256
__global__ __launch_bounds__(256) void projmlp_k(
    const unsigned short* __restrict__ Z, const unsigned short* __restrict__ A2,
    const unsigned short* __restrict__ PW2, const unsigned short* __restrict__ W1M,
    const float* __restrict__ pb2, const float* __restrict__ lg2, const float* __restrict__ lb2,
    const float* __restrict__ mb1, unsigned short* __restrict__ t, unsigned short* __restrict__ gout,
    int shift)
{
  __shared__ __align__(16) unsigned short Als[2][2048];
  __shared__ __align__(16) unsigned short Bls[2][8192];
  __shared__ __align__(16) unsigned short hL[16384];   // [8 kt][64 row][32 swizzled]
  const int tid = threadIdx.x, wid = tid >> 6, lane = tid & 63, gq = lane >> 4, l15 = lane & 15;
  const int wc = wid;                 // 4 waves, wr = 0
  const int row0 = blockIdx.x * 64;

  const int rA = tid >> 2, pA = tid & 3;
  const int lbA = pA ^ ((rA >> 1) & 3);
  const unsigned short* gAz = &Z[(size_t)(row0 + rA)*256 + lbA*8];
  const unsigned short* gAa = &A2[(size_t)(row0 + rA)*128 + lbA*8];
  const unsigned short* gB1[4];
  const unsigned short* gB2[4];
  #pragma unroll
  for (int i = 0; i < 4; ++i){
    int s = tid + 256*i, r = s >> 2, p = s & 3, lb = p ^ ((r >> 1) & 3);
    gB1[i] = &PW2[(size_t)r*384 + lb*8];
    gB2[i] = &W1M[(size_t)r*256 + lb*8];
  }

  f4v acc[4][4] = {};

  auto stage1 = [&](int kt, int buf){
    if (kt < 8) gl16(gAz + kt*32, &Als[buf][tid*8]);
    else        gl16(gAa + (kt - 8)*32, &Als[buf][tid*8]);
    #pragma unroll
    for (int i = 0; i < 4; ++i) gl16(gB1[i] + kt*32, &Bls[buf][(tid + 256*i)*8]);
  };
  auto stage2 = [&](int cb, int kt, int buf){
    #pragma unroll
    for (int i = 0; i < 4; ++i) gl16(gB2[i] + (size_t)cb*65536 + kt*32, &Bls[buf][(tid + 256*i)*8]);
  };
  auto compute = [&](const unsigned short* A, const unsigned short* B){
    frag_ab af[4], bv[4];
    #pragma unroll
    for (int a = 0; a < 4; ++a){ int r = a*16 + l15; int pb = gq ^ ((r >> 1) & 3);
      af[a] = *(const frag_ab*)&A[r*32 + pb*8]; }
    #pragma unroll
    for (int b = 0; b < 4; ++b){ int r = wc*64 + b*16 + l15; int pb = gq ^ ((r >> 1) & 3);
      bv[b] = *(const frag_ab*)&B[r*32 + pb*8]; }
    #pragma unroll
    for (int a = 0; a < 4; ++a)
      #pragma unroll
      for (int b = 0; b < 4; ++b)
        acc[a][b] = MFMA_BF16(af[a], bv[b], acc[a][b], 0, 0, 0);
  };

  // ---- phase 1: K = 384
  stage1(0, 0);
  __syncthreads();
  for (int kt = 0; kt < 12; kt += 2){
    stage1(kt + 1, 1);
    compute(Als[0], Bls[0]);
    __syncthreads();
    if (kt + 2 < 12) stage1(kt + 2, 0);
    compute(Als[1], Bls[1]);
    __syncthreads();
  }

  float* red = (float*)&Als[0][0];
  // pass 1: residual + t write + row stats
  #pragma unroll
  for (int a = 0; a < 4; ++a){
    #pragma unroll
    for (int r = 0; r < 4; ++r){
      const int grow = row0 + a*16 + gq*4 + r;
      int win = grow >> 8, tok = grow & 255;
      int bb = win >> 4, whh = (win >> 2) & 3, www = win & 3, rr = tok >> 4, cc = tok & 15;
      int srow = (bb*64 + ((whh*16 + rr + shift) & 63))*64 + ((www*16 + cc + shift) & 63);
      float s1 = 0.f, s2 = 0.f;
      #pragma unroll
      for (int b = 0; b < 4; ++b){
        int bcol = wc*64 + b*16 + l15;
        float v = h2f(t[(size_t)srow*256 + bcol]) + acc[a][b][r] + pb2[bcol];
        acc[a][b][r] = v;
        t[(size_t)srow*256 + bcol] = f2h(v);
        s1 += v; s2 += v*v;
      }
      s1 += __shfl_xor(s1, 1); s2 += __shfl_xor(s2, 1);
      s1 += __shfl_xor(s1, 2); s2 += __shfl_xor(s2, 2);
      s1 += __shfl_xor(s1, 4); s2 += __shfl_xor(s2, 4);
      s1 += __shfl_xor(s1, 8); s2 += __shfl_xor(s2, 8);
      if (l15 == 0){
        int rl = a*16 + gq*4 + r;
        red[rl*8 + wc*2]     = s1;
        red[rl*8 + wc*2 + 1] = s2;
      }
    }
  }
  __syncthreads();
  // pass 2: LN -> hL (staging-swizzled, tile-row order)
  #pragma unroll
  for (int a = 0; a < 4; ++a){
    #pragma unroll
    for (int r = 0; r < 4; ++r){
      int rl = a*16 + gq*4 + r;
      float s1 = red[rl*8] + red[rl*8+2] + red[rl*8+4] + red[rl*8+6];
      float s2 = red[rl*8+1] + red[rl*8+3] + red[rl*8+5] + red[rl*8+7];
      float mu = s1 * (1.0f/256.0f);
      float var = s2 * (1.0f/256.0f) - mu*mu;
      float rstd = rsqrtf(var + 1e-5f);
      #pragma unroll
      for (int b = 0; b < 4; ++b){
        int bcol = wc*64 + b*16 + l15;
        float hv = (acc[a][b][r] - mu)*rstd*lg2[bcol] + lb2[bcol];
        int ktc = bcol >> 5, pc = (bcol >> 3) & 3, ec = bcol & 7;
        hL[ktc*2048 + rl*32 + ((pc ^ ((rl >> 1) & 3)))*8 + ec] = f2b(hv);
      }
    }
  }
  __syncthreads();

  // ---- phase 2: g = gelu(h @ W1M^T), 2 col-blocks
  for (int cb = 0; cb < 2; ++cb){
    #pragma unroll
    for (int a = 0; a < 4; ++a)
      #pragma unroll
      for (int b = 0; b < 4; ++b)
        acc[a][b] = f4v{0.f, 0.f, 0.f, 0.f};
    stage2(cb, 0, 0);
    __syncthreads();
    for (int kt = 0; kt < 8; kt += 2){
      stage2(cb, kt + 1, 1);
      compute(&hL[kt*2048], Bls[0]);
      __syncthreads();
      if (kt + 2 < 8) stage2(cb, kt + 2, 0);
      compute(&hL[(kt + 1)*2048], Bls[1]);
      __syncthreads();
    }
    #pragma unroll
    for (int a = 0; a < 4; ++a){
      #pragma unroll
      for (int r = 0; r < 4; ++r){
        const int grow = row0 + a*16 + gq*4 + r;
        int win = grow >> 8, tok = grow & 255;
        int bb = win >> 4, whh = (win >> 2) & 3, www = win & 3, rr = tok >> 4, cc = tok & 15;
        int srow = (bb*64 + ((whh*16 + rr + shift) & 63))*64 + ((www*16 + cc + shift) & 63);
        #pragma unroll
        for (int b = 0; b < 4; ++b){
          int gcol = cb*256 + wc*64 + b*16 + l15;
          float xq = acc[a][b][r] + mb1[gcol];
          float x3 = xq*xq*xq;
          float e = hexp2(xq*2.3022115f + x3*0.10294856f);
          float gl = xq - xq*hrcp(e + 1.0f);
          gout[(size_t)srow*512 + gcol] = f2b(gl);
        }
      }
    }
  }
}

// ---------------------------------------------------------------- windowed attention (known-good round-5 version)
__global__ __launch_bounds__(512, 4) void attn_k(const unsigned short* __restrict__ qg_,
    const unsigned short* __restrict__ kg_, const unsigned short* __restrict__ vt_,
    const unsigned short* __restrict__ biasP, unsigned short* __restrict__ ob, int shift)
{
  __shared__ __align__(16) unsigned short Kl[16384];   // [256 tok][64 hd], 8-chunk XOR by row&7
  __shared__ __align__(16) unsigned short Vl[16384];   // [64 hd][256 tok(permuted)], 16B-chunk XOR by hd&15
  const int tid = threadIdx.x, wid = tid >> 6, lane = tid & 63, g = lane >> 4, q15 = lane & 15;
  const int blk = blockIdx.x, win = blk >> 2, head = blk & 3;
  const int wh = (win >> 2) & 3, ww = win & 3;
  const unsigned short* kg = kg_ + (size_t)blk*16384;
  const unsigned short* vg = vt_ + (size_t)blk*16384;
  const unsigned short* qg = qg_ + (size_t)blk*16384;
  const int var = shift ? (((wh == 3) ? 2 : 0) | ((ww == 3) ? 1 : 0)) : 0;
  const unsigned short* bT = biasP + ((size_t)var*4 + head)*65536;

  #pragma unroll
  for (int it = 0; it < 4; ++it){
    int s = it*512 + tid;
    int r = s >> 3, lb = (s & 7) ^ (r & 7);
    gl16(&kg[r*64 + lb*8], &Kl[s*8]);
    int hd = s >> 5, cc = s & 31, cs = (cc & 16) | ((cc & 15) ^ (hd & 15));
    gl16(&vg[hd*256 + cs*8], &Vl[s*8]);
  }
  __syncthreads();

  const f4v Z4 = {0.f, 0.f, 0.f, 0.f};
  for (int c = 0; c < 2; ++c){
    const int nq = wid*32 + c*16 + q15;          // this lane's query token
    const int qb = wid*2 + c;                    // wave-uniform query block
    frag_ab qf0 = *(const frag_ab*)&qg[nq*64 + g*8];
    frag_ab qf1 = *(const frag_ab*)&qg[nq*64 + 32 + g*8];
    unsigned int pk[32];
    float vsum = 0.f;
    #pragma unroll
    for (int t2 = 0; t2 < 16; ++t2){
      int r = t2*16 + q15;
      f4v a = Z4;
      { int pb = g ^ (r & 7);
        frag_ab ak = *(const frag_ab*)&Kl[r*64 + pb*8];
        a = MFMA_BF16(ak, qf0, a, 0, 0, 0); }
      { int pb = (4 + g) ^ (r & 7);
        frag_ab ak = *(const frag_ab*)&Kl[r*64 + pb*8];
        a = MFMA_BF16(ak, qf1, a, 0, 0, 0); }
      u4v bb = *(const u4v*)&bT[((qb*16 + t2)*16 + q15)*16 + g*4];
      float p0 = hexp2(a[0] + b2f(bb[0]));
      float p1 = hexp2(a[1] + b2f(bb[1]));
      float p2 = hexp2(a[2] + b2f(bb[2]));
      float p3 = hexp2(a[3] + b2f(bb[3]));
      vsum += (p0 + p1) + (p2 + p3);
      pk[2*t2]   = cvtpk(p0, p1);
      pk[2*t2+1] = cvtpk(p2, p3);
    }
    vsum += __shfl_xor(vsum, 16);
    vsum += __shfl_xor(vsum, 32);
    float inv = 1.0f / vsum;
    float invl[4];
    #pragma unroll
    for (int r = 0; r < 4; ++r) invl[r] = __shfl(inv, g*4 + r);
    f4v oc[4];
    #pragma unroll
    for (int nn = 0; nn < 4; ++nn) oc[nn] = Z4;
    __builtin_amdgcn_s_setprio(1);
    #pragma unroll
    for (int s = 0; s < 8; ++s){
      union { frag_ab f; unsigned int u[4]; } pa;
      pa.u[0] = pk[4*s + 0];
      pa.u[1] = pk[4*s + 1];
      pa.u[2] = pk[4*s + 2];
      pa.u[3] = pk[4*s + 3];
      #pragma unroll
      for (int nn = 0; nn < 4; ++nn){
        int hd = nn*16 + q15;
        int cc = s*4 + g;
        int cs = (cc & 16) | ((cc & 15) ^ (hd & 15));
        frag_ab bv = *(const frag_ab*)&Vl[hd*256 + cs*8];
        oc[nn] = MFMA_BF16(pa.f, bv, oc[nn], 0, 0, 0);
      }
    }
    __builtin_amdgcn_s_setprio(0);
    #pragma unroll
    for (int nn = 0; nn < 4; ++nn)
      #pragma unroll
      for (int r = 0; r < 4; ++r){
        int qq = wid*32 + c*16 + g*4 + r;
        ob[((size_t)(win*256 + qq))*256 + head*64 + nn*16 + q15] = f2b(oc[nn][r] * invl[r]);
      }
  }
}

// ---------------------------------------------------------------- host
extern "C" void kernel_launch(void* const* d_in, const int* in_sizes, int n_in,
                              void* d_out, int out_size, void* d_ws, size_t ws_size,
                              hipStream_t stream)
{
  (void)in_sizes; (void)n_in; (void)out_size; (void)ws_size;
  const float* x      = (const float*)d_in[0];
  const float* conv_w = (const float*)d_in[1];
  const float* bn_g   = (const float*)d_in[2];
  const float* bn_b   = (const float*)d_in[3];
  const float* bn_m   = (const float*)d_in[4];
  const float* bn_v   = (const float*)d_in[5];
  const float* ln1_g  = (const float*)d_in[6];
  const float* ln1_b  = (const float*)d_in[7];
  const float* qkv_w  = (const float*)d_in[8];
  const float* qkv_b  = (const float*)d_in[9];
  const float* proj_w = (const float*)d_in[10];
  const float* proj_b = (const float*)d_in[11];
  const float* rpb    = (const float*)d_in[12];
  const float* mem_b  = (const float*)d_in[13];
  const float* down_w = (const float*)d_in[14];
  const float* down_b = (const float*)d_in[15];
  const float* up_w   = (const float*)d_in[16];
  const float* up_b   = (const float*)d_in[17];
  const float* ln2_g  = (const float*)d_in[18];
  const float* ln2_b  = (const float*)d_in[19];
  const float* mlp_w1 = (const float*)d_in[20];
  const float* mlp_b1 = (const float*)d_in[21];
  const float* mlp_w2 = (const float*)d_in[22];
  const float* mlp_b2 = (const float*)d_in[23];

  char* ws = (char*)d_ws;
  unsigned short* tbuf  = (unsigned short*)(ws + OFF_T);   // f16 trunk
  unsigned short* xpb   = (unsigned short*)(ws + OFF_R1);
  unsigned short* qbuf  = (unsigned short*)(ws + OFF_R1);
  unsigned short* kbuf  = (unsigned short*)(ws + OFF_R1 + 16777216ull);
  unsigned short* gbuf  = (unsigned short*)(ws + OFF_R1);
  unsigned short* vtbuf = (unsigned short*)(ws + OFF_VT);
  unsigned short* zbuf  = (unsigned short*)(ws + OFF_ZH);  // z -> o -> znext
  unsigned short* abuf  = (unsigned short*)(ws + OFF_A);
  unsigned short* convwb = (unsigned short*)(ws + OFF_WB + WB_CONVW);
  unsigned short* qkvwb  = (unsigned short*)(ws + OFF_WB + WB_QKVW);
  unsigned short* projwb = (unsigned short*)(ws + OFF_WB + WB_PROJW);
  unsigned short* mlp1wb = (unsigned short*)(ws + OFF_WB + WB_MLP1W);
  unsigned short* mlp2wb = (unsigned short*)(ws + OFF_WB + WB_MLP2W);
  unsigned short* W1b    = (unsigned short*)(ws + OFF_WB + WB_W1);
  unsigned short* W2Tb   = (unsigned short*)(ws + OFF_WB + WB_W2T);
  float*          blogf  = (float*)(ws + OFF_WB + WB_BLOG);
  float*          convS  = (float*)(ws + OFF_WB + WB_CS);
  float*          convSh = (float*)(ws + OFF_WB + WB_CSH);
  unsigned short* biasPb = (unsigned short*)(ws + OFF_WB + WB_BIASP);
  unsigned short* pw2b   = (unsigned short*)(ws + OFF_WB + WB_PW2);
  float*          pb2f   = (float*)(ws + OFF_WB + WB_PB2);

  prep_k<<<20036, 256, 0, stream>>>(conv_w, bn_g, bn_b, bn_m, bn_v, qkv_w, proj_w, mlp_w1, mlp_w2,
                                    mem_b, down_w, down_b, up_w, rpb,
                                    convwb, qkvwb, projwb, mlp1wb, mlp2wb, W1b, W2Tb, biasPb,
                                    blogf, convS, convSh);
  prep2_k<<<1540, 256, 0, stream>>>(proj_w, up_b, proj_b, W2Tb, pw2b, pb2f);
  pad_k<<<528, 256, 0, stream>>>(x, xpb);
  { Ep ep{convS, convSh, ln1_g, ln1_b, tbuf, nullptr, zbuf, nullptr, nullptr, nullptr, nullptr, nullptr, 0};
    g512_k<M_CONV,64,256,576,256,0><<<dim3(512,1), 256, 0, stream>>>(xpb, convwb, ep); }

  static const int tb[4] = {0, 1, 5, 6};
  for (int i = 0; i < 4; ++i){
    int shift = (i & 1) ? 8 : 0;
    int shift_next = ((i + 1) & 1) ? 8 : 0;
    { Ep ep{qkv_b + i*768, nullptr, nullptr, nullptr, nullptr, nullptr, nullptr, nullptr, qbuf, kbuf, vtbuf, nullptr, 0};
      g512_k<M_QKV,64,256,256,256,1><<<dim3(3,512), 256, 0, stream>>>(zbuf, qkvwb + (size_t)i*196608, ep); }
    attn_k<<<512, 512, 0, stream>>>(qbuf, kbuf, vtbuf, biasPb + (size_t)tb[i]*262144, zbuf, shift);
    { Ep ep{blogf + i*128, nullptr, nullptr, nullptr, nullptr, nullptr, abuf, nullptr, nullptr, nullptr, nullptr, nullptr, 0};
      g512_k<M_MEM1S,128,128,256,256,0><<<dim3(256,1), 256, 0, stream>>>(zbuf, W1b + (size_t)i*32768, ep); }
    projmlp_k<<<512, 256, 0, stream>>>(zbuf, abuf, pw2b + (size_t)i*98304, mlp1wb + (size_t)i*131072,
                                       pb2f + i*256, ln2_g + i*256, ln2_b + i*256, mlp_b1 + i*512,
                                       tbuf, gbuf, shift);
    if (i < 3){
      Ep ep{mlp_b2 + i*256, nullptr, ln1_g + (i+1)*256, ln1_b + (i+1)*256, tbuf, nullptr, nullptr, zbuf, nullptr, nullptr, nullptr, nullptr, shift_next};
      g512_k<M_MLP2LN,64,256,512,256,0><<<dim3(512,1), 256, 0, stream>>>(gbuf, mlp2wb + (size_t)i*131072, ep);
    } else {
      Ep ep{mlp_b2 + i*256, nullptr, nullptr, nullptr, tbuf, (float*)d_out, nullptr, nullptr, nullptr, nullptr, nullptr, nullptr, 0};
      g512_k<M_MLP2OUT,64,256,512,256,0><<<dim3(512,1), 256, 0, stream>>>(gbuf, mlp2wb + (size_t)i*131072, ep);
    }
  }
}

// Round 11
// 609.746 us; speedup vs baseline: 1.1786x; 1.1786x over previous
//
#include <hip/hip_runtime.h>

// ---------------------------------------------------------------- types/helpers
using frag_ab = __attribute__((ext_vector_type(8))) short;   // bf16x8 MFMA operand
using f4v     = __attribute__((ext_vector_type(4))) float;   // MFMA accumulator
using u8v     = __attribute__((ext_vector_type(8))) unsigned short;
using u4v     = __attribute__((ext_vector_type(4))) unsigned short;

__device__ __forceinline__ float b2f(unsigned short u){
  return __uint_as_float(((unsigned int)u) << 16);
}
__device__ __forceinline__ unsigned short f2b(float f){
  unsigned int x = __float_as_uint(f);
  unsigned int r = x + 0x7fffu + ((x >> 16) & 1u);
  return (unsigned short)(r >> 16);
}
__device__ __forceinline__ float h2f(unsigned short u){
  _Float16 h; __builtin_memcpy(&h, &u, 2); return (float)h;
}
__device__ __forceinline__ unsigned short f2h(float f){
  _Float16 h = (_Float16)f; unsigned short u; __builtin_memcpy(&u, &h, 2); return u;
}
__device__ __forceinline__ float hexp2(float x){
#if __has_builtin(__builtin_amdgcn_exp2f)
  return __builtin_amdgcn_exp2f(x);
#else
  return exp2f(x);
#endif
}
__device__ __forceinline__ float hrcp(float x){
#if __has_builtin(__builtin_amdgcn_rcpf)
  return __builtin_amdgcn_rcpf(x);
#else
  return 1.0f / x;
#endif
}
__device__ __forceinline__ unsigned int cvtpk(float lo, float hi){
  unsigned int r;
  asm("v_cvt_pk_bf16_f32 %0, %1, %2" : "=v"(r) : "v"(lo), "v"(hi));
  return r;
}
// async global->LDS, 16B per lane; dest must be linear (wave base + lane*16)
__device__ __forceinline__ void gl16(const void* g, void* l){
  __builtin_amdgcn_global_load_lds(
      (const __attribute__((address_space(1))) unsigned int*)g,
      (__attribute__((address_space(3))) unsigned int*)l, 16, 0, 0);
}

#define MFMA_BF16 __builtin_amdgcn_mfma_f32_16x16x32_bf16

// ---------------------------------------------------------------- ws layout (bytes)
static constexpr size_t OFF_T   = 0;                       // t f16 [32768][256]
static constexpr size_t OFF_R1  = 33554432ull;             // Xp | q+k | g (mlp hidden)
static constexpr size_t OFF_V   = OFF_R1 + 37748736ull;    // h (LN2 out)
static constexpr size_t OFF_VT  = OFF_V + 16777216ull;     // vT (permuted)
static constexpr size_t OFF_ZH  = OFF_VT + 16777216ull;    // z | o | znext
static constexpr size_t OFF_A   = OFF_ZH + 16777216ull;    // a bf16 [32768][128]
static constexpr size_t OFF_WB  = OFF_A + 8388608ull;      // converted weights
static constexpr size_t WB_CONVW = 0;          // 256*576*2
static constexpr size_t WB_QKVW  = 294912;     // 4*768*256*2
static constexpr size_t WB_PROJW = 1867776;    // (kept for prep_k layout)
static constexpr size_t WB_MLP1W = 2392064;    // 4*512*256*2
static constexpr size_t WB_MLP2W = 3440640;    // 4*256*512*2
static constexpr size_t WB_W1    = 4489216;    // 4*128*256*2 (pre-scaled by log2e)
static constexpr size_t WB_W2T   = 4751360;    // 4*256*128*2
static constexpr size_t WB_BLOG  = 5013504;    // 4*128 f32 (pre-scaled by log2e)
static constexpr size_t WB_CS    = 5015552;    // 256 f32
static constexpr size_t WB_CSH   = 5016576;    // 256 f32
static constexpr size_t WB_BIASP = 5017600;    // 10*4*65536*2 premasked,*log2e
static constexpr size_t WB_PW2   = WB_BIASP + 5242880;  // projW2 combined [4][256][384]*2
static constexpr size_t WB_PB2   = WB_PW2 + 786432;     // pb2 [4][256] f32

// ---------------------------------------------------------------- prep
__global__ __launch_bounds__(256) void prep_k(
    const float* __restrict__ conv_w, const float* __restrict__ bn_g, const float* __restrict__ bn_b,
    const float* __restrict__ bn_m, const float* __restrict__ bn_v,
    const float* __restrict__ qkv_w, const float* __restrict__ proj_w,
    const float* __restrict__ mlp_w1, const float* __restrict__ mlp_w2,
    const float* __restrict__ mem_b, const float* __restrict__ down_w, const float* __restrict__ down_b,
    const float* __restrict__ up_w, const float* __restrict__ rpb,
    unsigned short* convwb, unsigned short* qkvwb, unsigned short* projwb,
    unsigned short* mlp1wb, unsigned short* mlp2wb, unsigned short* W1b, unsigned short* W2Tb,
    unsigned short* biasPb, float* blogf, float* convS, float* convSh)
{
  int idx = blockIdx.x * 256 + threadIdx.x;
  if (idx < 256){
    float s = bn_g[idx] * rsqrtf(bn_v[idx] + 1e-5f);
    convS[idx] = s; convSh[idx] = bn_b[idx] - bn_m[idx] * s; return;
  }
  idx -= 256;
  if (idx < 147456){  // conv weight reorder: [co][t9*64+ci]
    int co = idx / 576, kk = idx % 576;
    int t9 = kk >> 6, ci = kk & 63, ky = t9 / 3, kx = t9 % 3;
    convwb[idx] = f2b(conv_w[((co*64 + ci)*3 + ky)*3 + kx]); return;
  }
  idx -= 147456;
  if (idx < 786432){ qkvwb[idx] = f2b(qkv_w[idx]); return; }
  idx -= 786432;
  if (idx < 262144){ projwb[idx] = f2b(proj_w[idx]); return; }
  idx -= 262144;
  if (idx < 524288){ mlp1wb[idx] = f2b(mlp_w1[idx]); return; }
  idx -= 524288;
  if (idx < 524288){ mlp2wb[idx] = f2b(mlp_w2[idx]); return; }
  idx -= 524288;
  if (idx < 131072){  // W1[i][s][c] = log2e * sum_j mem[i][s][j]*down[i][j][c]
    int i = idx >> 15, rem = idx & 32767, s = rem >> 8, c = rem & 255;
    float acc = 0.f;
    for (int j = 0; j < 32; ++j) acc += mem_b[(i*128 + s)*32 + j] * down_w[(i*32 + j)*256 + c];
    W1b[idx] = f2b(acc * 1.44269504f); return;
  }
  idx -= 131072;
  if (idx < 131072){  // W2T[i][c][s] = sum_j mem[i][s][j]*up[i][c][j]
    int i = idx >> 15, rem = idx & 32767, c = rem >> 7, s = rem & 127;
    float acc = 0.f;
    for (int j = 0; j < 32; ++j) acc += mem_b[(i*128 + s)*32 + j] * up_w[(i*256 + c)*32 + j];
    W2Tb[idx] = f2b(acc); return;
  }
  idx -= 131072;
  if (idx < 512){  // blog[i][s] = log2e * mem[i][s]·down_b[i]
    int i = idx >> 7, s = idx & 127;
    float acc = 0.f;
    for (int j = 0; j < 32; ++j) acc += mem_b[(i*128 + s)*32 + j] * down_b[i*32 + j];
    blogf[idx] = acc * 1.44269504f; return;
  }
  idx -= 512;
  if (idx < 2621440){  // premasked bias tables [t][h][qb][kb][q15][cm], * log2(e)
    int t = idx >> 18, h = (idx >> 16) & 3, rest = idx & 65535;
    int qb = rest >> 12, kb = (rest >> 8) & 15, q15 = (rest >> 4) & 15, cm = rest & 15;
    int layer, var;
    if (t == 0){ layer = 0; var = 0; }
    else if (t <= 4){ layer = 1; var = t - 1; }
    else if (t == 5){ layer = 2; var = 0; }
    else { layer = 3; var = t - 6; }
    int ri = (qb - kb + 15)*31 + (q15 - cm + 15);
    float b = rpb[((size_t)layer*961 + ri)*4 + h];
    bool mk = ((var & 2) && ((qb < 8) != (kb < 8))) || ((var & 1) && ((q15 < 8) != (cm < 8)));
    if (mk) b -= 100.0f;
    biasPb[idx] = f2b(b * 1.44269504f);
  }
}

// prep2: combined proj|mem-recon weight  W'[i][o][0:256]=proj_w, [256:384]=0.1*(proj_w@W2T)
__global__ __launch_bounds__(256) void prep2_k(const float* __restrict__ proj_w,
    const float* __restrict__ up_b, const float* __restrict__ proj_b,
    const unsigned short* __restrict__ W2Tb, unsigned short* __restrict__ pw2, float* __restrict__ pb2)
{
  int idx = blockIdx.x * 256 + threadIdx.x;
  if (idx < 1024){  // pb2[i][o] = proj_b + 0.1 * up_b @ proj_w^T
    int i = idx >> 8, o = idx & 255;
    float acc = proj_b[i*256 + o];
    for (int c = 0; c < 256; ++c) acc += 0.1f * up_b[i*256 + c] * proj_w[((size_t)(i*256 + o))*256 + c];
    pb2[idx] = acc; return;
  }
  idx -= 1024;
  if (idx < 262144){  // proj part
    int i = idx >> 16, rem = idx & 65535, o = rem >> 8, c = rem & 255;
    pw2[((size_t)(i*256 + o))*384 + c] = f2b(proj_w[((size_t)(i*256 + o))*256 + c]); return;
  }
  idx -= 262144;
  if (idx < 131072){  // Wc part
    int i = idx >> 15, rem = idx & 32767, o = rem >> 7, s = rem & 127;
    float acc = 0.f;
    for (int c = 0; c < 256; ++c)
      acc += proj_w[((size_t)(i*256 + o))*256 + c] * b2f(W2Tb[(i*256 + c)*128 + s]);
    pw2[((size_t)(i*256 + o))*384 + 256 + s] = f2b(0.1f * acc);
  }
}

// ---------------------------------------------------------------- pad: NCHW f32 -> padded NHWC bf16 [8][66][66][64]
__global__ __launch_bounds__(256) void pad_k(const float* __restrict__ x, unsigned short* __restrict__ xp)
{
  const int bid = blockIdx.x;           // 8*66
  const int b = bid / 66, hp = bid % 66;
  const int tid = threadIdx.x;
  unsigned short* orow = xp + ((size_t)(b*66 + hp))*66*64;
  const u8v Z8 = {0,0,0,0,0,0,0,0};
  if (hp == 0 || hp == 65){
    for (int s = tid; s < 528; s += 256) *(u8v*)&orow[s*8] = Z8;
    return;
  }
  __shared__ float ls[64][65];
  const int h = hp - 1;
  {
    int cc = tid >> 2, w4 = (tid & 3)*16;
    const float* src = &x[((size_t)(b*64 + cc)*64 + h)*64 + w4];
    #pragma unroll
    for (int j = 0; j < 4; ++j){
      float4 v = *(const float4*)&src[j*4];
      ls[w4 + j*4 + 0][cc] = v.x; ls[w4 + j*4 + 1][cc] = v.y;
      ls[w4 + j*4 + 2][cc] = v.z; ls[w4 + j*4 + 3][cc] = v.w;
    }
  }
  __syncthreads();
  if (tid < 16){
    int wp = (tid >> 3) * 65;
    *(u8v*)&orow[(size_t)wp*64 + (tid & 7)*8] = Z8;
  }
  int w = tid >> 2, c0 = (tid & 3)*16;
  u8v o0, o1;
  #pragma unroll
  for (int e = 0; e < 8; ++e){ o0[e] = f2b(ls[w][c0+e]); o1[e] = f2b(ls[w][c0+8+e]); }
  *(u8v*)&orow[(size_t)(w+1)*64 + c0] = o0;
  *(u8v*)&orow[(size_t)(w+1)*64 + c0 + 8] = o1;
}

// ---------------------------------------------------------------- unified GEMM, fused epilogues
// trunk t is f16 (unsigned short storage)
struct Ep {
  const float* c0; const float* c1;
  const float* lg; const float* lb;
  unsigned short* t; float* outp;
  unsigned short* o0; unsigned short* o2;
  unsigned short* q; unsigned short* k; unsigned short* v;
  const unsigned short* in0;   // second A source for PROJLN
  int shift;
};
enum { M_CONV=0, M_QKV=1, M_MEM1S=2, M_PROJLN=3, M_MLP1=4, M_MLP2LN=5, M_MLP2OUT=6 };

template<int MODE, int TM, int TN, int KC, int NT, int GX>
__global__ __launch_bounds__(NT) void g512_k(const unsigned short* __restrict__ X,
                                             const unsigned short* __restrict__ W, Ep ep)
{
  __shared__ __align__(16) unsigned short Als[2][TM*32];
  __shared__ __align__(16) unsigned short Bls[2][TN*32];
  const int tid = threadIdx.x, wid = tid >> 6, lane = tid & 63, g = lane >> 4, l15 = lane & 15;
  constexpr int NW = TN/64;
  const int wr = wid / NW, wc = wid % NW;
  const int row0 = (GX ? blockIdx.y : blockIdx.x) * TM;
  const int col0 = (GX ? blockIdx.x : blockIdx.y) * TN;
  constexpr int KT = KC >> 5;
  constexpr int NA = (TM*4)/NT, NB = (TN*4)/NT;

  const unsigned short* gA[NA]; const unsigned short* gA2[NA]; int rbA[NA];
  #pragma unroll
  for (int i = 0; i < NA; ++i){
    int s = tid + NT*i, r = s >> 2, p = s & 3, lb = p ^ ((r >> 1) & 3);
    gA2[i] = nullptr;
    if constexpr (MODE == M_CONV){
      int ar = row0 + r, bi = ar >> 12, h = (ar >> 6) & 63, w = ar & 63;
      rbA[i] = ((bi*66 + h + 1)*66 + (w + 1))*64 + lb*8; gA[i] = nullptr;
    } else {
      constexpr int KA = (MODE == M_PROJLN) ? 256 : KC;
      gA[i] = &X[(size_t)(row0 + r)*KA + lb*8]; rbA[i] = 0;
      if constexpr (MODE == M_PROJLN) gA2[i] = &ep.in0[(size_t)(row0 + r)*128 + lb*8];
    }
  }
  const unsigned short* gB[NB];
  #pragma unroll
  for (int i = 0; i < NB; ++i){
    int s = tid + NT*i, r = s >> 2, p = s & 3, lb = p ^ ((r >> 1) & 3);
    gB[i] = &W[(size_t)(col0 + r)*KC + lb*8];
  }

  f4v acc[4][4] = {};

  auto stage = [&](int kt, int buf){
    #pragma unroll
    for (int i = 0; i < NA; ++i){
      if constexpr (MODE == M_CONV){
        int t9 = kt >> 1, ky = t9 / 3, kx = t9 - ky*3;
        int koff = ((ky - 1)*66 + (kx - 1))*64 + (kt & 1)*32;
        gl16(X + rbA[i] + koff, &Als[buf][(tid + NT*i)*8]);
      } else if constexpr (MODE == M_PROJLN){
        if (kt < 8) gl16(gA[i] + kt*32, &Als[buf][(tid + NT*i)*8]);
        else        gl16(gA2[i] + (kt - 8)*32, &Als[buf][(tid + NT*i)*8]);
      } else {
        gl16(gA[i] + kt*32, &Als[buf][(tid + NT*i)*8]);
      }
    }
    #pragma unroll
    for (int i = 0; i < NB; ++i) gl16(gB[i] + kt*32, &Bls[buf][(tid + NT*i)*8]);
  };
  auto compute = [&](const unsigned short* A, const unsigned short* B){
    frag_ab af[4], bv[4];
    #pragma unroll
    for (int a = 0; a < 4; ++a){ int r = wr*64 + a*16 + l15; int pb = g ^ ((r >> 1) & 3);
      af[a] = *(const frag_ab*)&A[r*32 + pb*8]; }
    #pragma unroll
    for (int b = 0; b < 4; ++b){ int r = wc*64 + b*16 + l15; int pb = g ^ ((r >> 1) & 3);
      bv[b] = *(const frag_ab*)&B[r*32 + pb*8]; }
    #pragma unroll
    for (int a = 0; a < 4; ++a)
      #pragma unroll
      for (int b = 0; b < 4; ++b)
        acc[a][b] = MFMA_BF16(af[a], bv[b], acc[a][b], 0, 0, 0);
  };

  stage(0, 0);
  __syncthreads();
  for (int kt = 0; kt < KT; kt += 2){
    stage(kt + 1, 1);
    compute(Als[0], Bls[0]);
    __syncthreads();
    if (kt + 2 < KT) stage(kt + 2, 0);
    compute(Als[1], Bls[1]);
    __syncthreads();
  }

  float* red = (float*)&Als[0][0];

  if constexpr (MODE == M_QKV){
    const int which = col0 >> 8;          // 0=Q 1=K 2=V
    #pragma unroll
    for (int a = 0; a < 4; ++a){
      #pragma unroll
      for (int b = 0; b < 4; ++b){
        const int grow0 = row0 + wr*64 + a*16 + g*4;
        const int hd = b*16 + l15;
        const float bv = ep.c0[col0 + wc*64 + hd];
        if (which == 2){
          int tok0 = grow0 & 255;
          int pos = (tok0 & ~31) | ((tok0 & 12) << 1) | ((tok0 & 16) >> 2);
          u4v o;
          #pragma unroll
          for (int r = 0; r < 4; ++r) o[r] = f2b(acc[a][b][r] + bv);
          *(u4v*)&ep.v[(((size_t)((grow0 >> 8)*4 + wc)*64 + hd)*256) + pos] = o;
        } else {
          unsigned short* dst = (which == 0) ? ep.q : ep.k;
          float sc = (which == 0) ? 0.18033688f : 1.0f;   // 0.125 * log2(e) folded into Q
          #pragma unroll
          for (int r = 0; r < 4; ++r){
            int grow = grow0 + r;
            dst[(((size_t)(grow >> 8)*4 + wc)*256 + (grow & 255))*64 + hd] = f2b((acc[a][b][r] + bv) * sc);
          }
        }
      }
    }
  } else if constexpr (MODE == M_MEM1S){
    #pragma unroll
    for (int a = 0; a < 4; ++a){
      #pragma unroll
      for (int r = 0; r < 4; ++r){
        float s1 = 0.f;
        #pragma unroll
        for (int b = 0; b < 4; ++b){
          int bcol = wc*64 + b*16 + l15;
          float e = hexp2(acc[a][b][r] + ep.c0[bcol]);
          acc[a][b][r] = e; s1 += e;
        }
        s1 += __shfl_xor(s1, 1); s1 += __shfl_xor(s1, 2);
        s1 += __shfl_xor(s1, 4); s1 += __shfl_xor(s1, 8);
        if (l15 == 0){
          int rl = wr*64 + a*16 + g*4 + r;
          red[rl*NW + wc] = s1;
        }
      }
    }
    __syncthreads();
    #pragma unroll
    for (int a = 0; a < 4; ++a){
      #pragma unroll
      for (int r = 0; r < 4; ++r){
        int rl = wr*64 + a*16 + g*4 + r;
        float inv = 1.0f / (red[rl*NW] + red[rl*NW + 1]);
        int grow = row0 + rl;
        #pragma unroll
        for (int b = 0; b < 4; ++b){
          int bcol = wc*64 + b*16 + l15;
          ep.o0[(size_t)grow*128 + bcol] = f2b(acc[a][b][r] * inv);
        }
      }
    }
  } else if constexpr (MODE == M_MLP1){
    #pragma unroll
    for (int a = 0; a < 4; ++a)
      #pragma unroll
      for (int b = 0; b < 4; ++b)
        #pragma unroll
        for (int r = 0; r < 4; ++r){
          int grow = row0 + wr*64 + a*16 + g*4 + r;
          int gcol = col0 + wc*64 + b*16 + l15;
          float xq = acc[a][b][r] + ep.c0[gcol];
          float x3 = xq*xq*xq;
          float e = hexp2(xq*2.3022115f + x3*0.10294856f);
          float gl = xq - xq*hrcp(e + 1.0f);
          ep.o0[(size_t)grow*512 + gcol] = f2b(gl);
        }
  } else if constexpr (MODE == M_MLP2OUT){
    // last layer: t_new written straight to NCHW f32 output
    #pragma unroll
    for (int a = 0; a < 4; ++a){
      #pragma unroll
      for (int b = 0; b < 4; ++b){
        const int grow0 = row0 + wr*64 + a*16 + g*4;
        const int bcol = wc*64 + b*16 + l15;
        float4 vv;
        #pragma unroll
        for (int r = 0; r < 4; ++r)
          (&vv.x)[r] = h2f(ep.t[(size_t)(grow0 + r)*256 + bcol]) + acc[a][b][r] + ep.c0[bcol];
        *(float4*)&ep.outp[((size_t)((grow0 >> 12)*256 + bcol))*4096 + (grow0 & 4095)] = vv;
      }
    }
  } else {
    // M_CONV / M_PROJLN / M_MLP2LN : t_new (f16) + fused LayerNorm
    #pragma unroll
    for (int a = 0; a < 4; ++a){
      #pragma unroll
      for (int r = 0; r < 4; ++r){
        const int grow = row0 + wr*64 + a*16 + g*4 + r;
        int srow;
        if constexpr (MODE == M_PROJLN){
          int win = grow >> 8, tok = grow & 255;
          int bb = win >> 4, whh = (win >> 2) & 3, www = win & 3, rr = tok >> 4, cc = tok & 15;
          srow = (bb*64 + ((whh*16 + rr + ep.shift) & 63))*64 + ((www*16 + cc + ep.shift) & 63);
        } else srow = grow;
        float s1 = 0.f, s2 = 0.f;
        #pragma unroll
        for (int b = 0; b < 4; ++b){
          int bcol = wc*64 + b*16 + l15;
          float v = acc[a][b][r];
          if constexpr (MODE == M_CONV) v = fmaxf(v*ep.c0[bcol] + ep.c1[bcol], 0.f);
          else v = h2f(ep.t[(size_t)srow*256 + bcol]) + v + ep.c0[bcol];
          acc[a][b][r] = v;
          ep.t[(size_t)srow*256 + bcol] = f2h(v);
          s1 += v; s2 += v*v;
        }
        s1 += __shfl_xor(s1, 1); s2 += __shfl_xor(s2, 1);
        s1 += __shfl_xor(s1, 2); s2 += __shfl_xor(s2, 2);
        s1 += __shfl_xor(s1, 4); s2 += __shfl_xor(s2, 4);
        s1 += __shfl_xor(s1, 8); s2 += __shfl_xor(s2, 8);
        if (l15 == 0){
          int rl = wr*64 + a*16 + g*4 + r;
          red[rl*8 + wc*2]     = s1;
          red[rl*8 + wc*2 + 1] = s2;
        }
      }
    }
    __syncthreads();
    #pragma unroll
    for (int a = 0; a < 4; ++a){
      #pragma unroll
      for (int r = 0; r < 4; ++r){
        const int grow = row0 + wr*64 + a*16 + g*4 + r;
        int rl = wr*64 + a*16 + g*4 + r;
        float s1 = red[rl*8] + red[rl*8+2] + red[rl*8+4] + red[rl*8+6];
        float s2 = red[rl*8+1] + red[rl*8+3] + red[rl*8+5] + red[rl*8+7];
        float mu = s1 * (1.0f/256.0f);
        float var = s2 * (1.0f/256.0f) - mu*mu;
        float rstd = rsqrtf(var + 1e-5f);
        unsigned short* zo = (MODE == M_MLP2LN) ? ep.o2 : ep.o0;
        int drow;
        if constexpr (MODE == M_PROJLN){
          int win = grow >> 8, tok = grow & 255;
          int bb = win >> 4, whh = (win >> 2) & 3, www = win & 3, rr = tok >> 4, cc = tok & 15;
          drow = (bb*64 + ((whh*16 + rr + ep.shift) & 63))*64 + ((www*16 + cc + ep.shift) & 63);
        } else {
          int bb2 = grow >> 12, h = (grow >> 6) & 63, w = grow & 63;
          int hs = (h - ep.shift) & 63, ws = (w - ep.shift) & 63;
          drow = (bb2*16 + (hs >> 4)*4 + (ws >> 4))*256 + (hs & 15)*16 + (ws & 15);
        }
        #pragma unroll
        for (int b = 0; b < 4; ++b){
          int bcol = wc*64 + b*16 + l15;
          float v = acc[a][b][r];
          zo[(size_t)drow*256 + bcol] = f2b((v - mu)*rstd*ep.lg[bcol] + ep.lb[bcol]);
        }
      }
    }
  }
}

// ---------------------------------------------------------------- windowed attention (known-good round-5 version)
__global__ __launch_bounds__(512, 4) void attn_k(const unsigned short* __restrict__ qg_,
    const unsigned short* __restrict__ kg_, const unsigned short* __restrict__ vt_,
    const unsigned short* __restrict__ biasP, unsigned short* __restrict__ ob, int shift)
{
  __shared__ __align__(16) unsigned short Kl[16384];   // [256 tok][64 hd], 8-chunk XOR by row&7
  __shared__ __align__(16) unsigned short Vl[16384];   // [64 hd][256 tok(permuted)], 16B-chunk XOR by hd&15
  const int tid = threadIdx.x, wid = tid >> 6, lane = tid & 63, g = lane >> 4, q15 = lane & 15;
  const int blk = blockIdx.x, win = blk >> 2, head = blk & 3;
  const int wh = (win >> 2) & 3, ww = win & 3;
  const unsigned short* kg = kg_ + (size_t)blk*16384;
  const unsigned short* vg = vt_ + (size_t)blk*16384;
  const unsigned short* qg = qg_ + (size_t)blk*16384;
  const int var = shift ? (((wh == 3) ? 2 : 0) | ((ww == 3) ? 1 : 0)) : 0;
  const unsigned short* bT = biasP + ((size_t)var*4 + head)*65536;

  #pragma unroll
  for (int it = 0; it < 4; ++it){
    int s = it*512 + tid;
    int r = s >> 3, lb = (s & 7) ^ (r & 7);
    gl16(&kg[r*64 + lb*8], &Kl[s*8]);
    int hd = s >> 5, cc = s & 31, cs = (cc & 16) | ((cc & 15) ^ (hd & 15));
    gl16(&vg[hd*256 + cs*8], &Vl[s*8]);
  }
  __syncthreads();

  const f4v Z4 = {0.f, 0.f, 0.f, 0.f};
  for (int c = 0; c < 2; ++c){
    const int nq = wid*32 + c*16 + q15;          // this lane's query token
    const int qb = wid*2 + c;                    // wave-uniform query block
    frag_ab qf0 = *(const frag_ab*)&qg[nq*64 + g*8];
    frag_ab qf1 = *(const frag_ab*)&qg[nq*64 + 32 + g*8];
    unsigned int pk[32];
    float vsum = 0.f;
    #pragma unroll
    for (int t2 = 0; t2 < 16; ++t2){
      int r = t2*16 + q15;
      f4v a = Z4;
      { int pb = g ^ (r & 7);
        frag_ab ak = *(const frag_ab*)&Kl[r*64 + pb*8];
        a = MFMA_BF16(ak, qf0, a, 0, 0, 0); }
      { int pb = (4 + g) ^ (r & 7);
        frag_ab ak = *(const frag_ab*)&Kl[r*64 + pb*8];
        a = MFMA_BF16(ak, qf1, a, 0, 0, 0); }
      u4v bb = *(const u4v*)&bT[((qb*16 + t2)*16 + q15)*16 + g*4];
      float p0 = hexp2(a[0] + b2f(bb[0]));
      float p1 = hexp2(a[1] + b2f(bb[1]));
      float p2 = hexp2(a[2] + b2f(bb[2]));
      float p3 = hexp2(a[3] + b2f(bb[3]));
      vsum += (p0 + p1) + (p2 + p3);
      pk[2*t2]   = cvtpk(p0, p1);
      pk[2*t2+1] = cvtpk(p2, p3);
    }
    vsum += __shfl_xor(vsum, 16);
    vsum += __shfl_xor(vsum, 32);
    float inv = 1.0f / vsum;
    float invl[4];
    #pragma unroll
    for (int r = 0; r < 4; ++r) invl[r] = __shfl(inv, g*4 + r);
    f4v oc[4];
    #pragma unroll
    for (int nn = 0; nn < 4; ++nn) oc[nn] = Z4;
    __builtin_amdgcn_s_setprio(1);
    #pragma unroll
    for (int s = 0; s < 8; ++s){
      union { frag_ab f; unsigned int u[4]; } pa;
      pa.u[0] = pk[4*s + 0];
      pa.u[1] = pk[4*s + 1];
      pa.u[2] = pk[4*s + 2];
      pa.u[3] = pk[4*s + 3];
      #pragma unroll
      for (int nn = 0; nn < 4; ++nn){
        int hd = nn*16 + q15;
        int cc = s*4 + g;
        int cs = (cc & 16) | ((cc & 15) ^ (hd & 15));
        frag_ab bv = *(const frag_ab*)&Vl[hd*256 + cs*8];
        oc[nn] = MFMA_BF16(pa.f, bv, oc[nn], 0, 0, 0);
      }
    }
    __builtin_amdgcn_s_setprio(0);
    #pragma unroll
    for (int nn = 0; nn < 4; ++nn)
      #pragma unroll
      for (int r = 0; r < 4; ++r){
        int qq = wid*32 + c*16 + g*4 + r;
        ob[((size_t)(win*256 + qq))*256 + head*64 + nn*16 + q15] = f2b(oc[nn][r] * invl[r]);
      }
  }
}

// ---------------------------------------------------------------- host
extern "C" void kernel_launch(void* const* d_in, const int* in_sizes, int n_in,
                              void* d_out, int out_size, void* d_ws, size_t ws_size,
                              hipStream_t stream)
{
  (void)in_sizes; (void)n_in; (void)out_size; (void)ws_size;
  const float* x      = (const float*)d_in[0];
  const float* conv_w = (const float*)d_in[1];
  const float* bn_g   = (const float*)d_in[2];
  const float* bn_b   = (const float*)d_in[3];
  const float* bn_m   = (const float*)d_in[4];
  const float* bn_v   = (const float*)d_in[5];
  const float* ln1_g  = (const float*)d_in[6];
  const float* ln1_b  = (const float*)d_in[7];
  const float* qkv_w  = (const float*)d_in[8];
  const float* qkv_b  = (const float*)d_in[9];
  const float* proj_w = (const float*)d_in[10];
  const float* proj_b = (const float*)d_in[11];
  const float* rpb    = (const float*)d_in[12];
  const float* mem_b  = (const float*)d_in[13];
  const float* down_w = (const float*)d_in[14];
  const float* down_b = (const float*)d_in[15];
  const float* up_w   = (const float*)d_in[16];
  const float* up_b   = (const float*)d_in[17];
  const float* ln2_g  = (const float*)d_in[18];
  const float* ln2_b  = (const float*)d_in[19];
  const float* mlp_w1 = (const float*)d_in[20];
  const float* mlp_b1 = (const float*)d_in[21];
  const float* mlp_w2 = (const float*)d_in[22];
  const float* mlp_b2 = (const float*)d_in[23];

  char* ws = (char*)d_ws;
  unsigned short* tbuf  = (unsigned short*)(ws + OFF_T);   // f16 trunk
  unsigned short* xpb   = (unsigned short*)(ws + OFF_R1);
  unsigned short* qbuf  = (unsigned short*)(ws + OFF_R1);
  unsigned short* kbuf  = (unsigned short*)(ws + OFF_R1 + 16777216ull);
  unsigned short* gbuf  = (unsigned short*)(ws + OFF_R1);
  unsigned short* hbuf  = (unsigned short*)(ws + OFF_V);
  unsigned short* vtbuf = (unsigned short*)(ws + OFF_VT);
  unsigned short* zbuf  = (unsigned short*)(ws + OFF_ZH);  // z -> o -> znext
  unsigned short* abuf  = (unsigned short*)(ws + OFF_A);
  unsigned short* convwb = (unsigned short*)(ws + OFF_WB + WB_CONVW);
  unsigned short* qkvwb  = (unsigned short*)(ws + OFF_WB + WB_QKVW);
  unsigned short* projwb = (unsigned short*)(ws + OFF_WB + WB_PROJW);
  unsigned short* mlp1wb = (unsigned short*)(ws + OFF_WB + WB_MLP1W);
  unsigned short* mlp2wb = (unsigned short*)(ws + OFF_WB + WB_MLP2W);
  unsigned short* W1b    = (unsigned short*)(ws + OFF_WB + WB_W1);
  unsigned short* W2Tb   = (unsigned short*)(ws + OFF_WB + WB_W2T);
  float*          blogf  = (float*)(ws + OFF_WB + WB_BLOG);
  float*          convS  = (float*)(ws + OFF_WB + WB_CS);
  float*          convSh = (float*)(ws + OFF_WB + WB_CSH);
  unsigned short* biasPb = (unsigned short*)(ws + OFF_WB + WB_BIASP);
  unsigned short* pw2b   = (unsigned short*)(ws + OFF_WB + WB_PW2);
  float*          pb2f   = (float*)(ws + OFF_WB + WB_PB2);

  prep_k<<<20036, 256, 0, stream>>>(conv_w, bn_g, bn_b, bn_m, bn_v, qkv_w, proj_w, mlp_w1, mlp_w2,
                                    mem_b, down_w, down_b, up_w, rpb,
                                    convwb, qkvwb, projwb, mlp1wb, mlp2wb, W1b, W2Tb, biasPb,
                                    blogf, convS, convSh);
  prep2_k<<<1540, 256, 0, stream>>>(proj_w, up_b, proj_b, W2Tb, pw2b, pb2f);
  pad_k<<<528, 256, 0, stream>>>(x, xpb);
  { Ep ep{convS, convSh, ln1_g, ln1_b, tbuf, nullptr, zbuf, nullptr, nullptr, nullptr, nullptr, nullptr, 0};
    g512_k<M_CONV,64,256,576,256,0><<<dim3(512,1), 256, 0, stream>>>(xpb, convwb, ep); }

  static const int tb[4] = {0, 1, 5, 6};
  for (int i = 0; i < 4; ++i){
    int shift = (i & 1) ? 8 : 0;
    int shift_next = ((i + 1) & 1) ? 8 : 0;
    { Ep ep{qkv_b + i*768, nullptr, nullptr, nullptr, nullptr, nullptr, nullptr, nullptr, qbuf, kbuf, vtbuf, nullptr, 0};
      g512_k<M_QKV,64,256,256,256,1><<<dim3(3,512), 256, 0, stream>>>(zbuf, qkvwb + (size_t)i*196608, ep); }
    attn_k<<<512, 512, 0, stream>>>(qbuf, kbuf, vtbuf, biasPb + (size_t)tb[i]*262144, zbuf, shift);
    { Ep ep{blogf + i*128, nullptr, nullptr, nullptr, nullptr, nullptr, abuf, nullptr, nullptr, nullptr, nullptr, nullptr, 0};
      g512_k<M_MEM1S,128,128,256,256,0><<<dim3(256,1), 256, 0, stream>>>(zbuf, W1b + (size_t)i*32768, ep); }
    { Ep ep{pb2f + i*256, nullptr, ln2_g + i*256, ln2_b + i*256, tbuf, nullptr, hbuf, nullptr, nullptr, nullptr, nullptr, abuf, shift};
      g512_k<M_PROJLN,64,256,384,256,0><<<dim3(512,1), 256, 0, stream>>>(zbuf, pw2b + (size_t)i*98304, ep); }
    { Ep ep{mlp_b1 + i*512, nullptr, nullptr, nullptr, nullptr, nullptr, gbuf, nullptr, nullptr, nullptr, nullptr, nullptr, 0};
      g512_k<M_MLP1,64,256,256,256,1><<<dim3(2,512), 256, 0, stream>>>(hbuf, mlp1wb + (size_t)i*131072, ep); }
    if (i < 3){
      Ep ep{mlp_b2 + i*256, nullptr, ln1_g + (i+1)*256, ln1_b + (i+1)*256, tbuf, nullptr, nullptr, zbuf, nullptr, nullptr, nullptr, nullptr, shift_next};
      g512_k<M_MLP2LN,64,256,512,256,0><<<dim3(512,1), 256, 0, stream>>>(gbuf, mlp2wb + (size_t)i*131072, ep);
    } else {
      Ep ep{mlp_b2 + i*256, nullptr, nullptr, nullptr, tbuf, (float*)d_out, nullptr, nullptr, nullptr, nullptr, nullptr, nullptr, 0};
      g512_k<M_MLP2OUT,64,256,512,256,0><<<dim3(512,1), 256, 0, stream>>>(gbuf, mlp2wb + (size_t)i*131072, ep);
    }
  }
}